// Round 8
// baseline (90.445 us; speedup 1.0000x reference)
//
#include <hip/hip_runtime.h>
#include <math.h>

namespace {

constexpr int kB = 4;
constexpr int kS = 4;
constexpr int kM = 1024;
constexpr int kN = 8192;
constexpr int kBS = kB * kS;
constexpr float kBig2 = 1e20f;  // sqrt(1e20) = 1e10 == reference BIG

constexpr int NSPL1 = 16;                        // K1: gt split, tiles of 128
constexpr int K1_TILE = 128;
constexpr int K1_BLOCKS = kBS * NSPL1;           // 256
constexpr int GSPL = 2;                          // K2: gt chunks of 1024
constexpr int MSPL = 8;                          // K2: pred tiles of 128
constexpr int K2_BLOCKS = kBS * GSPL * MSPL;     // 256
constexpr int GRID = K1_BLOCKS + K2_BLOCKS;      // 512 (2 blocks/CU, co-resident)

// ---- workspace layout (4-byte words) ----
constexpr int OFF_D1 = 0;                        // kBS*kM min-d2 bits
constexpr int OFF_DM = OFF_D1 + kBS * kM;        // kBS*kN min-d2 bits
constexpr int MINS_WORDS = kBS * kM + kBS * kN;  // 147456
constexpr int OFF_C4 = MINS_WORDS;               // float4[kBS*kN] gt {x,y,z,|g|^2}
constexpr int OFF_P4 = OFF_C4 + 4 * kBS * kN;    // float4[kBS*kM] pred {x,y,z,|p|^2}
constexpr int OFF_CUR = OFF_P4 + 4 * kBS * kM;   // 16 scatter cursors (memset 0)
constexpr int OFF_BAR = OFF_CUR + kBS;           // 2 grid-barrier counters (memset 0)
constexpr int ZERO_WORDS = kBS + 2;              // 72 B memset region

constexpr int INIT_BLOCKS = MINS_WORDS / 1024;   // 144 (uint4 stores)
constexpr int P4_BLOCKS = kBS * kM / 256;        // 64
constexpr int SCAT_BASE = INIT_BLOCKS + P4_BLOCKS;   // 208
constexpr int SCAT_BLOCKS = kB * kN / 256;       // 128 (208..335)

// grid barrier: release-arrive + acquire-spin. Counters zeroed per call by memset.
__device__ __forceinline__ void grid_barrier(unsigned int* c, bool wait) {
  __syncthreads();
  if (threadIdx.x == 0) {
    __threadfence();
    __hip_atomic_fetch_add(c, 1u, __ATOMIC_RELEASE, __HIP_MEMORY_SCOPE_AGENT);
    if (wait) {
      while (__hip_atomic_load(c, __ATOMIC_ACQUIRE, __HIP_MEMORY_SCOPE_AGENT) < (unsigned)GRID)
        __builtin_amdgcn_s_sleep(4);
    }
  }
  __syncthreads();
}

__global__ __launch_bounds__(256, 2) void kfused(const float* __restrict__ ret,
                                                 const float4* __restrict__ gt,
                                                 unsigned int* __restrict__ ws,
                                                 float* __restrict__ out) {
  const int bid = blockIdx.x, tid = threadIdx.x;
  __shared__ float4 tile[K1_TILE];
  __shared__ int wcnt[4][kS];
  __shared__ int bbase[kS];
  __shared__ float r1[4], r2[4];

  // ================= phase 0: init mins | build P4 | scatter gt =================
  if (bid < INIT_BLOCKS) {
    ((uint4*)ws)[bid * 256 + tid] = make_uint4(~0u, ~0u, ~0u, ~0u);
  } else if (bid < SCAT_BASE) {
    const int gi = (bid - INIT_BLOCKS) * 256 + tid;
    const float x = ret[gi * 3], y = ret[gi * 3 + 1], z = ret[gi * 3 + 2];
    ((float4*)(ws + OFF_P4))[gi] = make_float4(x, y, z, fmaf(x, x, fmaf(y, y, z * z)));
  } else if (bid < SCAT_BASE + SCAT_BLOCKS) {
    // block-aggregated scatter: one global atomicAdd per (block,label).
    const int idx = (bid - SCAT_BASE) * 256 + tid;  // single b per block
    const int b = idx >> 13;
    const int wave = tid >> 6, lane = tid & 63;
    const float4 q = gt[idx];
    const int s = (int)q.w;
    int rank = 0;
#pragma unroll
    for (int ss = 0; ss < kS; ++ss) {
      const unsigned long long m = __ballot(s == ss);
      if (lane == 0) wcnt[wave][ss] = (int)__popcll(m);
      if (s == ss) rank = (int)__popcll(m & ((1ull << lane) - 1ull));
    }
    __syncthreads();
    if (tid < kS) {
      const int tot = wcnt[0][tid] + wcnt[1][tid] + wcnt[2][tid] + wcnt[3][tid];
      bbase[tid] = atomicAdd((int*)ws + OFF_CUR + b * kS + tid, tot);  // relative
    }
    __syncthreads();
    int pos = bbase[s] + rank;
#pragma unroll
    for (int w = 0; w < 4; ++w)
      if (w < wave) pos += wcnt[w][s];
    const float gn = fmaf(q.x, q.x, fmaf(q.y, q.y, q.z * q.z));
    ((float4*)(ws + OFF_C4))[(b * kS + s) * kN + pos] = make_float4(q.x, q.y, q.z, gn);
  } else if (bid == GRID - 1 && tid == 0) {
    out[0] = 0.f;
  }

  grid_barrier(&ws[OFF_BAR], true);

  // ================= phase 1: distances (R6 kdist verbatim) =================
  {
    const float4* c4 = (const float4*)(ws + OFF_C4);
    const float4* p4 = (const float4*)(ws + OFF_P4);
    if (bid < K1_BLOCKS) {
      const int t = bid & (NSPL1 - 1);
      const int bs = bid >> 4;
      const int cnt = (int)__hip_atomic_load(&ws[OFF_CUR + bs], __ATOMIC_RELAXED,
                                             __HIP_MEMORY_SCOPE_AGENT);
      const float4 P0 = p4[bs * kM + tid];
      const float4 P1 = p4[bs * kM + tid + 256];
      const float4 P2 = p4[bs * kM + tid + 512];
      const float4 P3 = p4[bs * kM + tid + 768];
      const float ax0 = -2.f * P0.x, ay0 = -2.f * P0.y, az0 = -2.f * P0.z;
      const float ax1 = -2.f * P1.x, ay1 = -2.f * P1.y, az1 = -2.f * P1.z;
      const float ax2 = -2.f * P2.x, ay2 = -2.f * P2.y, az2 = -2.f * P2.z;
      const float ax3 = -2.f * P3.x, ay3 = -2.f * P3.y, az3 = -2.f * P3.z;
      float b0 = kBig2, b1 = kBig2, b2 = kBig2, b3 = kBig2;
      for (int start = t * K1_TILE; start < cnt; start += NSPL1 * K1_TILE) {
        __syncthreads();
        if (tid < K1_TILE) {
          const int j = start + tid;
          tile[tid] = (j < cnt) ? c4[bs * kN + j] : make_float4(0.f, 0.f, 0.f, kBig2);
        }
        __syncthreads();
#pragma unroll 8
        for (int j = 0; j < K1_TILE; ++j) {
          const float4 g = tile[j];  // wave-uniform -> LDS broadcast
          b0 = fminf(b0, fmaf(ax0, g.x, fmaf(ay0, g.y, fmaf(az0, g.z, g.w))));
          b1 = fminf(b1, fmaf(ax1, g.x, fmaf(ay1, g.y, fmaf(az1, g.z, g.w))));
          b2 = fminf(b2, fmaf(ax2, g.x, fmaf(ay2, g.y, fmaf(az2, g.z, g.w))));
          b3 = fminf(b3, fmaf(ax3, g.x, fmaf(ay3, g.y, fmaf(az3, g.z, g.w))));
        }
      }
      atomicMin(&ws[OFF_D1 + bs * kM + tid],       __float_as_uint(fmaxf(b0 + P0.w, 0.f)));
      atomicMin(&ws[OFF_D1 + bs * kM + tid + 256], __float_as_uint(fmaxf(b1 + P1.w, 0.f)));
      atomicMin(&ws[OFF_D1 + bs * kM + tid + 512], __float_as_uint(fmaxf(b2 + P2.w, 0.f)));
      atomicMin(&ws[OFF_D1 + bs * kM + tid + 768], __float_as_uint(fmaxf(b3 + P3.w, 0.f)));
    } else {
      int r = bid - K1_BLOCKS;
      const int ms = r & (MSPL - 1); r >>= 3;
      const int gs = r & (GSPL - 1); r >>= 1;
      const int bs = r;
      const int cnt = (int)__hip_atomic_load(&ws[OFF_CUR + bs], __ATOMIC_RELAXED,
                                             __HIP_MEMORY_SCOPE_AGENT);
      if (tid < K1_TILE) tile[tid] = p4[bs * kM + ms * K1_TILE + tid];
      __syncthreads();
      for (int base = gs * 1024; base < cnt; base += GSPL * 1024) {
        const int l0 = base + tid, l1 = l0 + 256, l2 = l0 + 512, l3 = l0 + 768;
        const bool v0 = l0 < cnt, v1 = l1 < cnt, v2 = l2 < cnt, v3 = l3 < cnt;
        const float4 G0 = v0 ? c4[bs * kN + l0] : make_float4(0.f, 0.f, 0.f, 0.f);
        const float4 G1 = v1 ? c4[bs * kN + l1] : make_float4(0.f, 0.f, 0.f, 0.f);
        const float4 G2 = v2 ? c4[bs * kN + l2] : make_float4(0.f, 0.f, 0.f, 0.f);
        const float4 G3 = v3 ? c4[bs * kN + l3] : make_float4(0.f, 0.f, 0.f, 0.f);
        const float ax0 = -2.f * G0.x, ay0 = -2.f * G0.y, az0 = -2.f * G0.z;
        const float ax1 = -2.f * G1.x, ay1 = -2.f * G1.y, az1 = -2.f * G1.z;
        const float ax2 = -2.f * G2.x, ay2 = -2.f * G2.y, az2 = -2.f * G2.z;
        const float ax3 = -2.f * G3.x, ay3 = -2.f * G3.y, az3 = -2.f * G3.z;
        float b0 = kBig2, b1 = kBig2, b2 = kBig2, b3 = kBig2;
#pragma unroll 8
        for (int mm = 0; mm < K1_TILE; ++mm) {
          const float4 p = tile[mm];  // wave-uniform broadcast
          b0 = fminf(b0, fmaf(ax0, p.x, fmaf(ay0, p.y, fmaf(az0, p.z, p.w))));
          b1 = fminf(b1, fmaf(ax1, p.x, fmaf(ay1, p.y, fmaf(az1, p.z, p.w))));
          b2 = fminf(b2, fmaf(ax2, p.x, fmaf(ay2, p.y, fmaf(az2, p.z, p.w))));
          b3 = fminf(b3, fmaf(ax3, p.x, fmaf(ay3, p.y, fmaf(az3, p.z, p.w))));
        }
        if (v0) atomicMin(&ws[OFF_DM + bs * kN + l0], __float_as_uint(fmaxf(b0 + G0.w, 0.f)));
        if (v1) atomicMin(&ws[OFF_DM + bs * kN + l1], __float_as_uint(fmaxf(b1 + G1.w, 0.f)));
        if (v2) atomicMin(&ws[OFF_DM + bs * kN + l2], __float_as_uint(fmaxf(b2 + G2.w, 0.f)));
        if (v3) atomicMin(&ws[OFF_DM + bs * kN + l3], __float_as_uint(fmaxf(b3 + G3.w, 0.f)));
      }
    }
  }

  // only the 16 reducer blocks need to wait here; the rest arrive and exit.
  grid_barrier(&ws[OFF_BAR + 1], bid < kBS);
  if (bid >= kBS) return;

  // ================= phase 2: per-(b,s) reduce (R6 krf verbatim) =================
  {
    const int bs = bid, b = bs >> 2;
    const int lane = tid & 63, wid = tid >> 6;
    const int cnt = (int)__hip_atomic_load(&ws[OFF_CUR + bs], __ATOMIC_RELAXED,
                                           __HIP_MEMORY_SCOPE_AGENT);
    float s1 = 0.f;
    for (int m = tid; m < kM; m += 256)
      s1 += sqrtf(fmaxf(__uint_as_float(ws[OFF_D1 + bs * kM + m]), 1e-12f));
    float s2 = 0.f;
    for (int i = tid; i < cnt; i += 256)
      s2 += sqrtf(fmaxf(__uint_as_float(ws[OFF_DM + bs * kN + i]), 1e-12f));
    for (int o = 32; o > 0; o >>= 1) {
      s1 += __shfl_down(s1, o);
      s2 += __shfl_down(s2, o);
    }
    if (lane == 0) { r1[wid] = s1; r2[wid] = s2; }
    __syncthreads();
    if (tid == 0) {
      const float a1 = r1[0] + r1[1] + r1[2] + r1[3];
      const float a2 = r2[0] + r2[1] + r2[2] + r2[3];
      int pres = 0;
      for (int s = 0; s < kS; ++s) {
        const int cs = (int)__hip_atomic_load(&ws[OFF_CUR + b * kS + s], __ATOMIC_RELAXED,
                                              __HIP_MEMORY_SCOPE_AGENT);
        pres += cs > 0 ? 1 : 0;
      }
      const float cham = cnt > 0 ? 0.5f * (a1 / (float)kM + a2 / (float)max(cnt, 1)) : 0.f;
      atomicAdd(out, cham / (float)(kB * max(pres, 1)));
    }
  }
}

}  // namespace

extern "C" void kernel_launch(void* const* d_in, const int* in_sizes, int n_in,
                              void* d_out, int out_size, void* d_ws, size_t ws_size,
                              hipStream_t stream) {
  const float* ret = (const float*)d_in[0];    // (B, S*M*3) f32 == (BS, M, 3)
  const float4* gt = (const float4*)d_in[1];   // (B, N, 4) f32
  unsigned int* ws = (unsigned int*)d_ws;

  // zero scatter cursors + barrier counters (72 B) — capture-legal async memset.
  hipMemsetAsync((char*)d_ws + (size_t)OFF_CUR * 4, 0, ZERO_WORDS * 4, stream);
  kfused<<<GRID, 256, 0, stream>>>(ret, gt, ws, (float*)d_out);
}

// Round 9
// 33.644 us; speedup vs baseline: 2.6883x; 2.6883x over previous
//
#include <hip/hip_runtime.h>
#include <math.h>

namespace {

constexpr int kB = 4;
constexpr int kS = 4;
constexpr int kM = 1024;
constexpr int kN = 8192;
constexpr int kBS = kB * kS;
constexpr float kBig2 = 1e20f;  // sqrt(1e20) = 1e10 == reference BIG

// ---- workspace layout (4-byte words) ----
constexpr int OFF_D1 = 0;                        // kBS*kM min-d2 bits
constexpr int OFF_DM = OFF_D1 + kBS * kM;        // kBS*kN min-d2 bits
constexpr int MINS_WORDS = kBS * kM + kBS * kN;  // 147456
constexpr int OFF_C4 = MINS_WORDS;               // float4[kBS*kN] gt {x,y,z,|g|^2}
constexpr int OFF_P4 = OFF_C4 + 4 * kBS * kN;    // float4[kBS*kM] pred {x,y,z,|p|^2}
constexpr int OFF_CUR = OFF_P4 + 4 * kBS * kM;   // 16 scatter cursors (RELATIVE, memset 0)

constexpr int INIT_BLOCKS = MINS_WORDS / 1024;   // 144 (uint4 stores)
constexpr int P4_BLOCKS = kBS * kM / 256;        // 64
constexpr int SCAT_BASE = INIT_BLOCKS + P4_BLOCKS;   // 208
constexpr int SCAT_BLOCKS = kB * kN / 256;       // 128

constexpr int NSPL1 = 16;                        // K1: gt split, tiles of 128
constexpr int K1_TILE = 128;
constexpr int K1_BLOCKS = kBS * NSPL1;           // 256
constexpr int GSPL = 2;                          // K2: gt chunks of 1024
constexpr int MSPL = 8;                          // K2: pred tiles of 128
constexpr int K2_BLOCKS = kBS * GSPL * MSPL;     // 256

// merged prep: min-buffer init (uint4, 0xFF = uint-min identity) | pred float4
// build | block-aggregated scatter (cursors pre-zeroed by hipMemsetAsync) | out=0.
__global__ __launch_bounds__(256) void kprepscat(const float* __restrict__ ret,
                                                 const float4* __restrict__ gt,
                                                 unsigned int* __restrict__ ws,
                                                 float* __restrict__ out) {
  const int blk = blockIdx.x, tid = threadIdx.x;
  if (blk < INIT_BLOCKS) {
    ((uint4*)ws)[blk * 256 + tid] = make_uint4(~0u, ~0u, ~0u, ~0u);
    if (blk == 0 && tid == 0) out[0] = 0.f;
    return;
  }
  if (blk < SCAT_BASE) {
    const int gi = (blk - INIT_BLOCKS) * 256 + tid;
    const float x = ret[gi * 3], y = ret[gi * 3 + 1], z = ret[gi * 3 + 2];
    ((float4*)(ws + OFF_P4))[gi] = make_float4(x, y, z, fmaf(x, x, fmaf(y, y, z * z)));
    return;
  }
  // scatter: one global atomicAdd per (block,label); cursors are bucket-relative.
  const int idx = (blk - SCAT_BASE) * 256 + tid;  // single b per block
  const int b = idx >> 13;
  const int wave = tid >> 6, lane = tid & 63;
  const float4 q = gt[idx];
  const int s = (int)q.w;
  __shared__ int wcnt[4][kS];
  __shared__ int bbase[kS];
  int rank = 0;
#pragma unroll
  for (int ss = 0; ss < kS; ++ss) {
    const unsigned long long m = __ballot(s == ss);
    if (lane == 0) wcnt[wave][ss] = (int)__popcll(m);
    if (s == ss) rank = (int)__popcll(m & ((1ull << lane) - 1ull));
  }
  __syncthreads();
  if (tid < kS) {
    const int tot = wcnt[0][tid] + wcnt[1][tid] + wcnt[2][tid] + wcnt[3][tid];
    bbase[tid] = atomicAdd((int*)ws + OFF_CUR + b * kS + tid, tot);
  }
  __syncthreads();
  int pos = bbase[s] + rank;
#pragma unroll
  for (int w = 0; w < 4; ++w)
    if (w < wave) pos += wcnt[w][s];
  const float gn = fmaf(q.x, q.x, fmaf(q.y, q.y, q.z * q.z));
  ((float4*)(ws + OFF_C4))[(b * kS + s) * kN + pos] = make_float4(q.x, q.y, q.z, gn);
}

// merged distance kernel, dot-expansion form: per pair 3 FMA + 1 min.
// K1 blocks: per (b,s,m) min over bucket. K2 blocks: per gt point min over M.
__global__ __launch_bounds__(256) void kdist(unsigned int* __restrict__ ws) {
  const int tid = threadIdx.x;
  __shared__ float4 tile[K1_TILE];
  const int* cur = (const int*)ws + OFF_CUR;   // relative counts
  const float4* c4 = (const float4*)(ws + OFF_C4);
  const float4* p4 = (const float4*)(ws + OFF_P4);

  if (blockIdx.x < K1_BLOCKS) {
    const int t = blockIdx.x & (NSPL1 - 1);
    const int bs = blockIdx.x >> 4;
    const int cnt = cur[bs];
    const float4 P0 = p4[bs * kM + tid];
    const float4 P1 = p4[bs * kM + tid + 256];
    const float4 P2 = p4[bs * kM + tid + 512];
    const float4 P3 = p4[bs * kM + tid + 768];
    const float ax0 = -2.f * P0.x, ay0 = -2.f * P0.y, az0 = -2.f * P0.z;
    const float ax1 = -2.f * P1.x, ay1 = -2.f * P1.y, az1 = -2.f * P1.z;
    const float ax2 = -2.f * P2.x, ay2 = -2.f * P2.y, az2 = -2.f * P2.z;
    const float ax3 = -2.f * P3.x, ay3 = -2.f * P3.y, az3 = -2.f * P3.z;
    float b0 = kBig2, b1 = kBig2, b2 = kBig2, b3 = kBig2;
    for (int start = t * K1_TILE; start < cnt; start += NSPL1 * K1_TILE) {
      __syncthreads();
      if (tid < K1_TILE) {
        const int j = start + tid;
        tile[tid] = (j < cnt) ? c4[bs * kN + j] : make_float4(0.f, 0.f, 0.f, kBig2);
      }
      __syncthreads();
#pragma unroll 8
      for (int j = 0; j < K1_TILE; ++j) {
        const float4 g = tile[j];  // wave-uniform -> LDS broadcast
        b0 = fminf(b0, fmaf(ax0, g.x, fmaf(ay0, g.y, fmaf(az0, g.z, g.w))));
        b1 = fminf(b1, fmaf(ax1, g.x, fmaf(ay1, g.y, fmaf(az1, g.z, g.w))));
        b2 = fminf(b2, fmaf(ax2, g.x, fmaf(ay2, g.y, fmaf(az2, g.z, g.w))));
        b3 = fminf(b3, fmaf(ax3, g.x, fmaf(ay3, g.y, fmaf(az3, g.z, g.w))));
      }
    }
    // +|p|^2 outside the min; clamp: negative bits would lose the uint-min.
    atomicMin(&ws[OFF_D1 + bs * kM + tid],       __float_as_uint(fmaxf(b0 + P0.w, 0.f)));
    atomicMin(&ws[OFF_D1 + bs * kM + tid + 256], __float_as_uint(fmaxf(b1 + P1.w, 0.f)));
    atomicMin(&ws[OFF_D1 + bs * kM + tid + 512], __float_as_uint(fmaxf(b2 + P2.w, 0.f)));
    atomicMin(&ws[OFF_D1 + bs * kM + tid + 768], __float_as_uint(fmaxf(b3 + P3.w, 0.f)));
  } else {
    int r = blockIdx.x - K1_BLOCKS;
    const int ms = r & (MSPL - 1); r >>= 3;
    const int gs = r & (GSPL - 1); r >>= 1;
    const int bs = r;
    const int cnt = cur[bs];
    if (tid < K1_TILE) tile[tid] = p4[bs * kM + ms * K1_TILE + tid];
    __syncthreads();
    for (int base = gs * 1024; base < cnt; base += GSPL * 1024) {
      const int l0 = base + tid, l1 = l0 + 256, l2 = l0 + 512, l3 = l0 + 768;
      const bool v0 = l0 < cnt, v1 = l1 < cnt, v2 = l2 < cnt, v3 = l3 < cnt;
      const float4 G0 = v0 ? c4[bs * kN + l0] : make_float4(0.f, 0.f, 0.f, 0.f);
      const float4 G1 = v1 ? c4[bs * kN + l1] : make_float4(0.f, 0.f, 0.f, 0.f);
      const float4 G2 = v2 ? c4[bs * kN + l2] : make_float4(0.f, 0.f, 0.f, 0.f);
      const float4 G3 = v3 ? c4[bs * kN + l3] : make_float4(0.f, 0.f, 0.f, 0.f);
      const float ax0 = -2.f * G0.x, ay0 = -2.f * G0.y, az0 = -2.f * G0.z;
      const float ax1 = -2.f * G1.x, ay1 = -2.f * G1.y, az1 = -2.f * G1.z;
      const float ax2 = -2.f * G2.x, ay2 = -2.f * G2.y, az2 = -2.f * G2.z;
      const float ax3 = -2.f * G3.x, ay3 = -2.f * G3.y, az3 = -2.f * G3.z;
      float b0 = kBig2, b1 = kBig2, b2 = kBig2, b3 = kBig2;
#pragma unroll 8
      for (int mm = 0; mm < K1_TILE; ++mm) {
        const float4 p = tile[mm];  // wave-uniform broadcast
        b0 = fminf(b0, fmaf(ax0, p.x, fmaf(ay0, p.y, fmaf(az0, p.z, p.w))));
        b1 = fminf(b1, fmaf(ax1, p.x, fmaf(ay1, p.y, fmaf(az1, p.z, p.w))));
        b2 = fminf(b2, fmaf(ax2, p.x, fmaf(ay2, p.y, fmaf(az2, p.z, p.w))));
        b3 = fminf(b3, fmaf(ax3, p.x, fmaf(ay3, p.y, fmaf(az3, p.z, p.w))));
      }
      if (v0) atomicMin(&ws[OFF_DM + bs * kN + l0], __float_as_uint(fmaxf(b0 + G0.w, 0.f)));
      if (v1) atomicMin(&ws[OFF_DM + bs * kN + l1], __float_as_uint(fmaxf(b1 + G1.w, 0.f)));
      if (v2) atomicMin(&ws[OFF_DM + bs * kN + l2], __float_as_uint(fmaxf(b2 + G2.w, 0.f)));
      if (v3) atomicMin(&ws[OFF_DM + bs * kN + l3], __float_as_uint(fmaxf(b3 + G3.w, 0.f)));
    }
  }
}

// fused epilogue: one block per (b,s); pres_b from cursors; atomicAdd into out.
__global__ __launch_bounds__(256) void krf(const unsigned int* __restrict__ ws,
                                           float* __restrict__ out) {
  const int tid = threadIdx.x, lane = tid & 63, wid = tid >> 6;
  const int bs = blockIdx.x, b = bs >> 2;
  const int* cur = (const int*)ws + OFF_CUR;   // relative counts
  const int cnt = cur[bs];
  float s1 = 0.f;
  for (int m = tid; m < kM; m += 256)
    s1 += sqrtf(fmaxf(__uint_as_float(ws[OFF_D1 + bs * kM + m]), 1e-12f));
  float s2 = 0.f;
  for (int i = tid; i < cnt; i += 256)
    s2 += sqrtf(fmaxf(__uint_as_float(ws[OFF_DM + bs * kN + i]), 1e-12f));
  for (int o = 32; o > 0; o >>= 1) {
    s1 += __shfl_down(s1, o);
    s2 += __shfl_down(s2, o);
  }
  __shared__ float r1[4], r2[4];
  if (lane == 0) { r1[wid] = s1; r2[wid] = s2; }
  __syncthreads();
  if (tid == 0) {
    const float a1 = r1[0] + r1[1] + r1[2] + r1[3];
    const float a2 = r2[0] + r2[1] + r2[2] + r2[3];
    int pres = 0;
    for (int s = 0; s < kS; ++s) pres += cur[b * kS + s] > 0 ? 1 : 0;
    const float cham = cnt > 0 ? 0.5f * (a1 / (float)kM + a2 / (float)max(cnt, 1)) : 0.f;
    atomicAdd(out, cham / (float)(kB * max(pres, 1)));
  }
}

}  // namespace

extern "C" void kernel_launch(void* const* d_in, const int* in_sizes, int n_in,
                              void* d_out, int out_size, void* d_ws, size_t ws_size,
                              hipStream_t stream) {
  const float* ret = (const float*)d_in[0];    // (B, S*M*3) f32 == (BS, M, 3)
  const float4* gt = (const float4*)d_in[1];   // (B, N, 4) f32
  unsigned int* ws = (unsigned int*)d_ws;
  float* out = (float*)d_out;

  // zero the 16 relative scatter cursors (64 B) — capture-legal async memset.
  hipMemsetAsync((char*)d_ws + (size_t)OFF_CUR * 4, 0, kBS * 4, stream);
  kprepscat<<<SCAT_BASE + SCAT_BLOCKS, 256, 0, stream>>>(ret, gt, ws, out);
  kdist<<<K1_BLOCKS + K2_BLOCKS, 256, 0, stream>>>(ws);
  krf<<<kBS, 256, 0, stream>>>(ws, out);
}